// Round 4
// baseline (189.370 us; speedup 1.0000x reference)
//
#include <hip/hip_runtime.h>
#include <hip/hip_bf16.h>

// T=6, B=2, Q=50 -> P=100 queries; N=8 targets; 72x72 -> 288x288 bilinear
// (align_corners=False, 4x => fixed weights); out C[B,Q,N] = 800 f32.
// R4: dice dot + row sums via mfma_f32_16x16x32_bf16. Block = (t, qgroup16,
// 8-outrow chunk); lane computes activations in A-fragment position
// (row=lane&15=query, k=8*(lane>>4)+j consecutive pixels); B = [g0..g7,ones,0..].
// iN/iD (conditioned IoU) stay f32 VALU + shfl reduce.

#define T_      6
#define P_      100
#define N_      8
#define HIN     72
#define SIN     (HIN*HIN)        // 5184
#define HOUT    288
#define S_OUT   (HOUT*HOUT)      // 82944
#define NQG     7                // query groups of 16 (100 -> 112 padded)
#define NCH     36               // pixel chunks per t (8 output rows each)
#define RPC     8                // output rows per chunk
#define PART_F  320              // floats per partial slot: L[9][16], S[9][16], iN[16], iD[16]
#define WS2_OFF (T_*NQG*NCH*PART_F)          // 483840
#define SUMG_OFF (WS2_OFF + T_*NQG*PART_F)   // +13440 = 497280
#define GCHUNK  8
#define NQUAD   (S_OUT/4)

typedef __attribute__((ext_vector_type(8))) short short8;
typedef __attribute__((ext_vector_type(4))) float f32x4;

__device__ __forceinline__ short f2bf(float f) {
    union { __hip_bfloat16 h; short s; } u;
    u.h = __float2bfloat16(f);
    return u.s;
}

__device__ __forceinline__ float fsigmoid(float x) {
    return __builtin_amdgcn_rcpf(1.0f + __expf(-x));
}

#define WRED(x) { x += __shfl_down(x,32); x += __shfl_down(x,16); x += __shfl_down(x,8); \
                  x += __shfl_down(x,4);  x += __shfl_down(x,2);  x += __shfl_down(x,1); }

// ---------------------------------------------------------------------------
// Kernel 1: MFMA partials. grid = T_*NQG*NCH blocks x 256 threads (4 waves).
// ---------------------------------------------------------------------------
__global__ __launch_bounds__(256) void mfma_partial(
    const float* __restrict__ predL, const float* __restrict__ predS,
    const float* __restrict__ tgt, float* __restrict__ ws)
{
    const int blk = blockIdx.x;                 // (t*NQG+qg)*NCH + ch
    const int t   = blk / (NQG*NCH);
    const int rem = blk % (NQG*NCH);
    const int qg  = rem / NCH;
    const int ch  = rem % NCH;

    const int lane = threadIdx.x & 63;
    const int wv   = threadIdx.x >> 6;
    const int arow = lane & 15;                 // A row (query) / B col (mask)
    const int kg   = lane >> 4;                 // k group 0..3
    const int klo  = kg * 8;                    // pixel offset within 32-px k-step
    const int cib  = 2*kg - 1;                  // input-col base offset

    const int q = min(qg*16 + arow, P_-1);
    const float* __restrict__ pLq = predL + ((size_t)t*P_ + q)*SIN;
    const float* __restrict__ pSq = predS + ((size_t)t*P_ + q)*SIN;
    const bool gvalid = (arow < 8);
    const bool gones  = (arow == 8);
    const float* __restrict__ gq = tgt + ((size_t)t*N_ + min(arow,7))*S_OUT;

    f32x4 accL = {0.f,0.f,0.f,0.f}, accS = {0.f,0.f,0.f,0.f};
    float iN = 0.f, iD = 0.f;
    const float WT[4] = {0.375f, 0.125f, 0.875f, 0.625f};
    const short ONEBF = (short)0x3F80;

    for (int rr = wv; rr < RPC; rr += 4) {
        const int orow = ch*RPC + rr;
        const int ry = orow & 3, j = orow >> 2;
        int y0 = (ry < 2) ? j-1 : j;
        int y1 = y0 + 1;
        y0 = max(y0, 0); y1 = min(y1, HIN-1);
        const float wt = WT[ry], wb = 1.0f - wt;
        const float* __restrict__ rL0 = pLq + y0*HIN;
        const float* __restrict__ rL1 = pLq + y1*HIN;
        const float* __restrict__ rS0 = pSq + y0*HIN;
        const float* __restrict__ rS1 = pSq + y1*HIN;
        const float* __restrict__ gp  = gq + (size_t)orow*HOUT + klo;

        for (int cc = 0; cc < 9; cc++) {
            const int ci = cc*8 + cib;
            const int cA = max(ci, 0);
            const int cB = ci + 1;
            const int cC = ci + 2;
            const int cD = min(ci + 3, HIN-1);

            // row interp: 4 taps per tensor
            const float vL0 = wt*rL0[cA] + wb*rL1[cA];
            const float vL1 = wt*rL0[cB] + wb*rL1[cB];
            const float vL2 = wt*rL0[cC] + wb*rL1[cC];
            const float vL3 = wt*rL0[cD] + wb*rL1[cD];
            const float vS0 = wt*rS0[cA] + wb*rS1[cA];
            const float vS1 = wt*rS0[cB] + wb*rS1[cB];
            const float vS2 = wt*rS0[cC] + wb*rS1[cC];
            const float vS3 = wt*rS0[cD] + wb*rS1[cD];

            // col interp: 8 consecutive output pixels
            float uL[8], uS[8];
            uL[0] = 0.375f*vL0 + 0.625f*vL1;  uS[0] = 0.375f*vS0 + 0.625f*vS1;
            uL[1] = 0.125f*vL0 + 0.875f*vL1;  uS[1] = 0.125f*vS0 + 0.875f*vS1;
            uL[2] = 0.875f*vL1 + 0.125f*vL2;  uS[2] = 0.875f*vS1 + 0.125f*vS2;
            uL[3] = 0.625f*vL1 + 0.375f*vL2;  uS[3] = 0.625f*vS1 + 0.375f*vS2;
            uL[4] = 0.375f*vL1 + 0.625f*vL2;  uS[4] = 0.375f*vS1 + 0.625f*vS2;
            uL[5] = 0.125f*vL1 + 0.875f*vL2;  uS[5] = 0.125f*vS1 + 0.875f*vS2;
            uL[6] = 0.875f*vL2 + 0.125f*vL3;  uS[6] = 0.875f*vS2 + 0.125f*vS3;
            uL[7] = 0.625f*vL2 + 0.375f*vL3;  uS[7] = 0.625f*vS2 + 0.375f*vS3;

            float aL[8], aS[8];
#pragma unroll
            for (int k = 0; k < 8; k++) { aL[k] = fsigmoid(uL[k]); aS[k] = fsigmoid(uS[k]); }

            // conditioned-IoU accumulators (f32, per-query via lane&15)
#pragma unroll
            for (int k = 0; k < 8; k++) {
                const float pl = (uL[k] > 0.f) ? aL[k] : 0.f;
                const float ps = (uS[k] > 0.f) ? aS[k] : 0.f;
                iN = fmaf(pl, ps, iN);
                iD += pl;
            }

            // A fragments (bf16)
            short8 fL, fS;
#pragma unroll
            for (int k = 0; k < 8; k++) { fL[k] = f2bf(aL[k]); fS[k] = f2bf(aS[k]); }

            // B fragment: cols 0-7 = g masks, col 8 = ones, cols 9-15 = 0
            short8 fB;
            if (gvalid) {
                const float4 gA = *(const float4*)(gp + cc*32);
                const float4 gB = *(const float4*)(gp + cc*32 + 4);
                fB[0]=f2bf(gA.x); fB[1]=f2bf(gA.y); fB[2]=f2bf(gA.z); fB[3]=f2bf(gA.w);
                fB[4]=f2bf(gB.x); fB[5]=f2bf(gB.y); fB[6]=f2bf(gB.z); fB[7]=f2bf(gB.w);
            } else {
                const short v = gones ? ONEBF : (short)0;
#pragma unroll
                for (int k = 0; k < 8; k++) fB[k] = v;
            }

            accL = __builtin_amdgcn_mfma_f32_16x16x32_bf16(fL, fB, accL, 0, 0, 0);
            accS = __builtin_amdgcn_mfma_f32_16x16x32_bf16(fS, fB, accS, 0, 0, 0);
        }
    }

    // --- block reduction ---
    __shared__ float cred[4][64][8];
#pragma unroll
    for (int e = 0; e < 4; e++) { cred[wv][lane][e] = accL[e]; cred[wv][lane][4+e] = accS[e]; }

    iN += __shfl_xor(iN, 16); iN += __shfl_xor(iN, 32);
    iD += __shfl_xor(iD, 16); iD += __shfl_xor(iD, 32);
    __shared__ float ired[4][16][2];
    if (lane < 16) { ired[wv][lane][0] = iN; ired[wv][lane][1] = iD; }
    __syncthreads();

    float* wsb = ws + (size_t)blk * PART_F;
    if (threadIdx.x < 64) {
        const int l = threadIdx.x;
        const int col = l & 15, rb = (l >> 4) * 4;
        if (col < 9) {
#pragma unroll
            for (int e = 0; e < 4; e++) {
                const float sLv = cred[0][l][e]+cred[1][l][e]+cred[2][l][e]+cred[3][l][e];
                const float sSv = cred[0][l][4+e]+cred[1][l][4+e]+cred[2][l][4+e]+cred[3][l][4+e];
                wsb[col*16 + rb + e] = sLv;
                wsb[144 + col*16 + rb + e] = sSv;
            }
        }
    }
    if (threadIdx.x < 16) {
        wsb[288 + threadIdx.x] = ired[0][threadIdx.x][0]+ired[1][threadIdx.x][0]
                               + ired[2][threadIdx.x][0]+ired[3][threadIdx.x][0];
        wsb[304 + threadIdx.x] = ired[0][threadIdx.x][1]+ired[1][threadIdx.x][1]
                               + ired[2][threadIdx.x][1]+ired[3][threadIdx.x][1];
    }
}

// ---------------------------------------------------------------------------
// Kernel 2: per-(t,n) target mask partial sums (f32 exact)
// ---------------------------------------------------------------------------
__global__ __launch_bounds__(256) void sumg_kernel(
    const float* __restrict__ tgt, float* __restrict__ ws)
{
    const int blk  = blockIdx.x;             // (t*8+n)*GCHUNK + c
    const int mask = blk / GCHUNK;
    const int c    = blk % GCHUNK;
    const float4* __restrict__ g = (const float4*)(tgt + (size_t)mask*S_OUT);
    const int per = NQUAD / GCHUNK;          // 2592
    float s = 0.f;
    const int end = (c+1)*per;
    for (int idx = c*per + threadIdx.x; idx < end; idx += 256) {
        float4 v = g[idx];
        s += v.x + v.y + v.z + v.w;
    }
    WRED(s);
    __shared__ float r[4];
    if ((threadIdx.x & 63) == 0) r[threadIdx.x >> 6] = s;
    __syncthreads();
    if (threadIdx.x == 0) ws[SUMG_OFF + blk] = r[0]+r[1]+r[2]+r[3];
}

// ---------------------------------------------------------------------------
// Kernel 3: reduce NCH chunk partials -> per-(t,qg) sums
// ---------------------------------------------------------------------------
__global__ __launch_bounds__(320) void reduce_kernel(float* __restrict__ ws)
{
    const int tq = blockIdx.x;               // t*NQG + qg
    for (int s = threadIdx.x; s < PART_F; s += 320) {
        float acc = 0.f;
        const float* base = ws + (size_t)tq*NCH*PART_F + s;
#pragma unroll 4
        for (int c = 0; c < NCH; c++) acc += base[(size_t)c*PART_F];
        ws[WS2_OFF + (size_t)tq*PART_F + s] = acc;
    }
}

// ---------------------------------------------------------------------------
// Kernel 4: finalize 800 outputs
// ---------------------------------------------------------------------------
__global__ __launch_bounds__(64) void final_kernel(
    const float* __restrict__ pirL, const float* __restrict__ pirS,
    const int* __restrict__ refidx, const float* __restrict__ ws,
    float* __restrict__ out)
{
    const int gid = blockIdx.x*64 + threadIdx.x;
    if (gid >= P_*N_) return;
    const int p = gid >> 3, n = gid & 7;
    const int b = p / 50, qloc = p % 50;
    const int qg = p >> 4, row = p & 15;
    const int rg0 = refidx[0], rg1 = refidx[1] + 4;   // ref_indices[b] + b*(N/B)
    const bool isref = (n == rg0) || (n == rg1);

    float acc = 0.f;
    for (int t = 0; t < T_; t++) {
        const float* b2 = ws + WS2_OFF + (size_t)(t*NQG + qg)*PART_F;
        const float dL = b2[n*16 + row];
        const float sL = b2[128 + row];          // ones column (col 8)
        const float dS = b2[144 + n*16 + row];
        const float sS = b2[144 + 128 + row];
        const float iN = b2[288 + row];
        const float iD = b2[304 + row];
        float gS = 0.f;
#pragma unroll
        for (int c = 0; c < GCHUNK; c++) gS += ws[SUMG_OFF + (t*8+n)*GCHUNK + c];

        const float diceL = (2.f*dL + 1.f) / (sL + gS + 1.f);
        const float diceS = (2.f*dS + 1.f) / (sS + gS + 1.f);
        const float iou   = (iN + 1.f) / (iD + 1.f);
        const int ib = ((t*2 + b)*50 + qloc)*2;
        const float l0 = pirL[ib], l1 = pirL[ib+1];
        const float m0 = pirS[ib], m1 = pirS[ib+1];
        const float pl = isref ? 1.f/(1.f + __expf(l1 - l0)) : 1.f/(1.f + __expf(l0 - l1));
        const float ps = isref ? 1.f/(1.f + __expf(m1 - m0)) : 1.f/(1.f + __expf(m0 - m1));
        acc += diceL + diceS + iou + pl + ps;
    }
    out[gid] = -acc * (1.0f / (float)T_);
}

extern "C" void kernel_launch(void* const* d_in, const int* in_sizes, int n_in,
                              void* d_out, int out_size, void* d_ws, size_t ws_size,
                              hipStream_t stream) {
    const float* predL = (const float*)d_in[0];   // [6,2,50,72,72]
    const float* predS = (const float*)d_in[1];   // [6,2,50,72,72]
    const float* pirL  = (const float*)d_in[2];   // [6,2,50,2]
    const float* pirS  = (const float*)d_in[3];   // [6,2,50,2]
    const float* tgt   = (const float*)d_in[4];   // [6,8,288,288]
    const int*   refix = (const int*)d_in[5];     // [2]
    float* ws  = (float*)d_ws;                    // ~497,664 floats (~1.99 MB)
    float* out = (float*)d_out;                   // 800 floats

    mfma_partial<<<T_*NQG*NCH, 256, 0, stream>>>(predL, predS, tgt, ws);
    sumg_kernel<<<T_*N_*GCHUNK, 256, 0, stream>>>(tgt, ws);
    reduce_kernel<<<T_*NQG, 320, 0, stream>>>(ws);
    final_kernel<<<(P_*N_ + 63)/64, 64, 0, stream>>>(pirL, pirS, refix, ws, out);
}

// Round 6
// 108.596 us; speedup vs baseline: 1.7438x; 1.7438x over previous
//
#include <hip/hip_runtime.h>
#include <hip/hip_bf16.h>

// T=6, B=2, Q=50 -> P=100 queries; N=8 targets; 72x72 -> 288x288 bilinear
// (align_corners=False, 4x => fixed weights); out C[B,Q,N] = 800 f32.
// R6: == R5 with the swizzle/k-step indexing fix: fragment-read offset must
// fold 64*ks into the PRE-swizzle address (XOR mask spans bit 6).

#define T_      6
#define P_      100
#define N_      8
#define HIN     72
#define SIN     (HIN*HIN)        // 5184
#define HOUT    288
#define S_OUT   (HOUT*HOUT)      // 82944
#define NQG     7                // query groups of 16 (100 -> 112 padded)
#define NCH     36               // pixel slabs per (t,qg): 2304 px each
#define PART_F  320              // floats per partial slot
#define WS2_OFF (T_*NQG*NCH*PART_F)          // 483840
#define SUMG_OFF (WS2_OFF + T_*NQG*PART_F)   // 497280
#define GCHUNK  8
#define NQUAD   (S_OUT/4)        // 20736 float4 per mask
#define WLDS    6144             // per-wave LDS: actL 2K, actS 2K, g 2K

typedef __attribute__((ext_vector_type(8))) short short8;
typedef __attribute__((ext_vector_type(4))) float f32x4;
typedef __attribute__((ext_vector_type(2))) float f32x2;

__device__ __forceinline__ unsigned cvt_pk_bf16(float lo, float hi) {
    unsigned r;
    asm("v_cvt_pk_bf16_f32 %0, %1, %2" : "=v"(r) : "v"(lo), "v"(hi));
    return r;
}

__device__ __forceinline__ f32x2 sigm2(f32x2 u) {
    f32x2 e;
    e.x = __expf(-u.x);
    e.y = __expf(-u.y);
    f32x2 d = e + 1.0f;
    f32x2 r;
    r.x = __builtin_amdgcn_rcpf(d.x);
    r.y = __builtin_amdgcn_rcpf(d.y);
    return r;
}

#define WRED(x) { x += __shfl_down(x,32); x += __shfl_down(x,16); x += __shfl_down(x,8); \
                  x += __shfl_down(x,4);  x += __shfl_down(x,2);  x += __shfl_down(x,1); }

// ---------------------------------------------------------------------------
// Kernel 1: act pipeline + MFMA. grid = T_*NQG*NCH, 256 threads (4 waves).
// ---------------------------------------------------------------------------
__global__ __launch_bounds__(256) void mfma_partial(
    const float* __restrict__ predL, const float* __restrict__ predS,
    const float* __restrict__ tgt, float* __restrict__ ws)
{
    __shared__ __align__(16) char smem[4*WLDS + 512];
    float* iredN = (float*)(smem + 4*WLDS);        // [4][16]
    float* iredD = (float*)(smem + 4*WLDS + 256);  // [4][16]
    float (*cred)[64][8] = (float (*)[64][8])smem; // aliased over act area (end only)

    const int blk = blockIdx.x;                 // (t*NQG+qg)*NCH + ch
    const int t   = blk / (NQG*NCH);
    const int rem = blk % (NQG*NCH);
    const int qg  = rem / NCH;
    const int ch  = rem % NCH;

    const int lane = threadIdx.x & 63;
    const int wv   = threadIdx.x >> 6;
    char* actL = smem + wv*WLDS;
    char* actS = actL + 2048;
    char* gpl  = actL + 4096;

    // act-compute roles: q = lane>>2 (query in group), c = lane&3 (quad slot)
    const int q = lane >> 2, c = lane & 3;
    const int qglob = min(qg*16 + q, P_-1);
    const float* __restrict__ pLq = predL + ((size_t)t*P_ + qglob)*SIN;
    const float* __restrict__ pSq = predS + ((size_t)t*P_ + qglob)*SIN;
    // g-stage roles: n = lane>>3, f = lane&7 (two float4 each: f and f+8)
    const int gn = lane >> 3, gf = lane & 7;
    const float4* __restrict__ gsrc = (const float4*)tgt + (size_t)(t*8 + gn)*NQUAD;
    const int gwoff = (gn*128 + 8*gf) ^ ((gn&7)<<4);

    // prefill B cols 8..15 (ones column + zeros), static across iters
    if (lane < 16) {
        *(uint2*)(gpl + ((8*128 + 8*lane) ^ 0)) = make_uint2(0x3F803F80u, 0x3F803F80u);
#pragma unroll
        for (int col = 9; col < 16; col++)
            *(uint2*)(gpl + ((col*128 + 8*lane) ^ ((col&7)<<4))) = make_uint2(0u, 0u);
    }

    f32x4 accL = {0.f,0.f,0.f,0.f}, accS = {0.f,0.f,0.f,0.f};
    float iN = 0.f, iD = 0.f;
    const int arow = lane & 15, kg = lane >> 4;

    for (int it = 0; it < 9; it++) {
        const int px0 = ch*2304 + it*256 + wv*64;   // wave's 64-px chunk

        // --- stage g chunk (8 masks x 64 px, bf16, swizzled [n][k]) ---
        {
            const int f4b = px0 >> 2;
            float4 ga = gsrc[f4b + gf];
            float4 gb = gsrc[f4b + gf + 8];
            uint2 pa, pb;
            pa.x = cvt_pk_bf16(ga.x, ga.y); pa.y = cvt_pk_bf16(ga.z, ga.w);
            pb.x = cvt_pk_bf16(gb.x, gb.y); pb.y = cvt_pk_bf16(gb.z, gb.w);
            *(uint2*)(gpl + gwoff) = pa;
            *(uint2*)(gpl + (gwoff ^ 64)) = pb;     // base bit6==0 pre-swz, so ^64 == +64
        }

        // --- compute acts for 4 quads (16 px) of query q, both tensors ---
#pragma unroll
        for (int s = 0; s < 4; s++) {
            const unsigned p = px0 + 4*(c + 4*s);
            const int row  = p / 288u;
            const int col4 = (p % 288u) >> 2;
            const int ry = row & 3, j = row >> 2;
            int y0 = (ry < 2) ? j-1 : j;
            int y1 = y0 + 1;
            y0 = max(y0, 0); y1 = min(y1, HIN-1);
            const float wt = 0.375f + 0.5f*(float)(ry>>1) - 0.25f*(float)(ry&1);
            const float wb = 1.0f - wt;
            const int im1 = max(col4-1, 0), ip1 = min(col4+1, HIN-1);
            const int o0 = y0*HIN, o1 = y1*HIN;

            f32x2 tm, tc, tp, bm, bc, bp;   // (L,S) pairs
            tm.x = pLq[o0+im1];  tm.y = pSq[o0+im1];
            tc.x = pLq[o0+col4]; tc.y = pSq[o0+col4];
            tp.x = pLq[o0+ip1];  tp.y = pSq[o0+ip1];
            bm.x = pLq[o1+im1];  bm.y = pSq[o1+im1];
            bc.x = pLq[o1+col4]; bc.y = pSq[o1+col4];
            bp.x = pLq[o1+ip1];  bp.y = pSq[o1+ip1];

            f32x2 vm = tm*wt + bm*wb;
            f32x2 vc = tc*wt + bc*wb;
            f32x2 vp = tp*wt + bp*wb;
            f32x2 u0 = vm*0.375f + vc*0.625f;
            f32x2 u1 = vm*0.125f + vc*0.875f;
            f32x2 u2 = vc*0.875f + vp*0.125f;
            f32x2 u3 = vc*0.625f + vp*0.375f;

            f32x2 a0 = sigm2(u0), a1 = sigm2(u1), a2 = sigm2(u2), a3 = sigm2(u3);

            // conditioned IoU (x = L, y = S)
            {
                float pl, ps;
                pl = (u0.x > 0.f) ? a0.x : 0.f; ps = (u0.y > 0.f) ? a0.y : 0.f;
                iN = fmaf(pl, ps, iN); iD += pl;
                pl = (u1.x > 0.f) ? a1.x : 0.f; ps = (u1.y > 0.f) ? a1.y : 0.f;
                iN = fmaf(pl, ps, iN); iD += pl;
                pl = (u2.x > 0.f) ? a2.x : 0.f; ps = (u2.y > 0.f) ? a2.y : 0.f;
                iN = fmaf(pl, ps, iN); iD += pl;
                pl = (u3.x > 0.f) ? a3.x : 0.f; ps = (u3.y > 0.f) ? a3.y : 0.f;
                iN = fmaf(pl, ps, iN); iD += pl;
            }

            uint2 wl, wsv;
            wl.x  = cvt_pk_bf16(a0.x, a1.x); wl.y  = cvt_pk_bf16(a2.x, a3.x);
            wsv.x = cvt_pk_bf16(a0.y, a1.y); wsv.y = cvt_pk_bf16(a2.y, a3.y);
            const int aoff = (q*128 + 8*(c + 4*s)) ^ ((q&7)<<4);
            *(uint2*)(actL + aoff) = wl;
            *(uint2*)(actS + aoff) = wsv;
        }

        __syncthreads();   // fence: LDS writes -> fragment reads

        // --- MFMA: 2 k-steps x 2 tensors ---
#pragma unroll
        for (int ks = 0; ks < 2; ks++) {
            // FIX (R6): fold 64*ks into the PRE-swizzle address; the XOR mask
            // ((arow&7)<<4) spans bit 6, so post-swizzle +64 carried into bit 7.
            const int fo = (arow*128 + 64*ks + 16*kg) ^ ((arow&7)<<4);
            short8 fAL = *(const short8*)(actL + fo);
            short8 fAS = *(const short8*)(actS + fo);
            short8 fB  = *(const short8*)(gpl  + fo);
            accL = __builtin_amdgcn_mfma_f32_16x16x32_bf16(fAL, fB, accL, 0, 0, 0);
            accS = __builtin_amdgcn_mfma_f32_16x16x32_bf16(fAS, fB, accS, 0, 0, 0);
        }
        __syncthreads();   // protect next iter's writes
    }

    // --- block reduction: C-frags + iou, matching R4 ws layout ---
    float t1 = iN + __shfl_down(iN, 1); const float iNq = t1 + __shfl_down(t1, 2);
    float t2 = iD + __shfl_down(iD, 1); const float iDq = t2 + __shfl_down(t2, 2);

    __syncthreads();       // done with act LDS; cred aliases it now
#pragma unroll
    for (int e = 0; e < 4; e++) { cred[wv][lane][e] = accL[e]; cred[wv][lane][4+e] = accS[e]; }
    if ((lane & 3) == 0) { iredN[wv*16 + q] = iNq; iredD[wv*16 + q] = iDq; }
    __syncthreads();

    float* wsb = ws + (size_t)blk * PART_F;
    if (threadIdx.x < 64) {
        const int l = threadIdx.x;
        const int colx = l & 15, rb = (l >> 4) * 4;
        if (colx < 9) {
#pragma unroll
            for (int e = 0; e < 4; e++) {
                const float sLv = cred[0][l][e]+cred[1][l][e]+cred[2][l][e]+cred[3][l][e];
                const float sSv = cred[0][l][4+e]+cred[1][l][4+e]+cred[2][l][4+e]+cred[3][l][4+e];
                wsb[colx*16 + rb + e] = sLv;
                wsb[144 + colx*16 + rb + e] = sSv;
            }
        }
    }
    if (threadIdx.x < 16) {
        wsb[288 + threadIdx.x] = iredN[threadIdx.x] + iredN[16+threadIdx.x]
                               + iredN[32+threadIdx.x] + iredN[48+threadIdx.x];
        wsb[304 + threadIdx.x] = iredD[threadIdx.x] + iredD[16+threadIdx.x]
                               + iredD[32+threadIdx.x] + iredD[48+threadIdx.x];
    }
}

// ---------------------------------------------------------------------------
// Kernel 2: per-(t,n) target mask partial sums (f32 exact)
// ---------------------------------------------------------------------------
__global__ __launch_bounds__(256) void sumg_kernel(
    const float* __restrict__ tgt, float* __restrict__ ws)
{
    const int blk  = blockIdx.x;             // (t*8+n)*GCHUNK + c
    const int mask = blk / GCHUNK;
    const int c    = blk % GCHUNK;
    const float4* __restrict__ g = (const float4*)(tgt + (size_t)mask*S_OUT);
    const int per = NQUAD / GCHUNK;          // 2592
    float s = 0.f;
    const int end = (c+1)*per;
    for (int idx = c*per + threadIdx.x; idx < end; idx += 256) {
        float4 v = g[idx];
        s += v.x + v.y + v.z + v.w;
    }
    WRED(s);
    __shared__ float r[4];
    if ((threadIdx.x & 63) == 0) r[threadIdx.x >> 6] = s;
    __syncthreads();
    if (threadIdx.x == 0) ws[SUMG_OFF + blk] = r[0]+r[1]+r[2]+r[3];
}

// ---------------------------------------------------------------------------
// Kernel 3: reduce NCH chunk partials -> per-(t,qg) sums
// ---------------------------------------------------------------------------
__global__ __launch_bounds__(320) void reduce_kernel(float* __restrict__ ws)
{
    const int tq = blockIdx.x;               // t*NQG + qg
    for (int s = threadIdx.x; s < PART_F; s += 320) {
        float acc = 0.f;
        const float* base = ws + (size_t)tq*NCH*PART_F + s;
#pragma unroll 4
        for (int c = 0; c < NCH; c++) acc += base[(size_t)c*PART_F];
        ws[WS2_OFF + (size_t)tq*PART_F + s] = acc;
    }
}

// ---------------------------------------------------------------------------
// Kernel 4: finalize 800 outputs
// ---------------------------------------------------------------------------
__global__ __launch_bounds__(64) void final_kernel(
    const float* __restrict__ pirL, const float* __restrict__ pirS,
    const int* __restrict__ refidx, const float* __restrict__ ws,
    float* __restrict__ out)
{
    const int gid = blockIdx.x*64 + threadIdx.x;
    if (gid >= P_*N_) return;
    const int p = gid >> 3, n = gid & 7;
    const int b = p / 50, qloc = p % 50;
    const int qg = p >> 4, row = p & 15;
    const int rg0 = refidx[0], rg1 = refidx[1] + 4;   // ref_indices[b] + b*(N/B)
    const bool isref = (n == rg0) || (n == rg1);

    float acc = 0.f;
    for (int t = 0; t < T_; t++) {
        const float* b2 = ws + WS2_OFF + (size_t)(t*NQG + qg)*PART_F;
        const float dL = b2[n*16 + row];
        const float sL = b2[128 + row];          // ones column (col 8)
        const float dS = b2[144 + n*16 + row];
        const float sS = b2[144 + 128 + row];
        const float iN = b2[288 + row];
        const float iD = b2[304 + row];
        float gS = 0.f;
#pragma unroll
        for (int c = 0; c < GCHUNK; c++) gS += ws[SUMG_OFF + (t*8+n)*GCHUNK + c];

        const float diceL = (2.f*dL + 1.f) / (sL + gS + 1.f);
        const float diceS = (2.f*dS + 1.f) / (sS + gS + 1.f);
        const float iou   = (iN + 1.f) / (iD + 1.f);
        const int ib = ((t*2 + b)*50 + qloc)*2;
        const float l0 = pirL[ib], l1 = pirL[ib+1];
        const float m0 = pirS[ib], m1 = pirS[ib+1];
        const float pl = isref ? 1.f/(1.f + __expf(l1 - l0)) : 1.f/(1.f + __expf(l0 - l1));
        const float ps = isref ? 1.f/(1.f + __expf(m1 - m0)) : 1.f/(1.f + __expf(m0 - m1));
        acc += diceL + diceS + iou + pl + ps;
    }
    out[gid] = -acc * (1.0f / (float)T_);
}

extern "C" void kernel_launch(void* const* d_in, const int* in_sizes, int n_in,
                              void* d_out, int out_size, void* d_ws, size_t ws_size,
                              hipStream_t stream) {
    const float* predL = (const float*)d_in[0];   // [6,2,50,72,72]
    const float* predS = (const float*)d_in[1];   // [6,2,50,72,72]
    const float* pirL  = (const float*)d_in[2];   // [6,2,50,2]
    const float* pirS  = (const float*)d_in[3];   // [6,2,50,2]
    const float* tgt   = (const float*)d_in[4];   // [6,8,288,288]
    const int*   refix = (const int*)d_in[5];     // [2]
    float* ws  = (float*)d_ws;                    // ~497,664 floats (~1.99 MB)
    float* out = (float*)d_out;                   // 800 floats

    mfma_partial<<<T_*NQG*NCH, 256, 0, stream>>>(predL, predS, tgt, ws);
    sumg_kernel<<<T_*N_*GCHUNK, 256, 0, stream>>>(tgt, ws);
    reduce_kernel<<<T_*NQG, 320, 0, stream>>>(ws);
    final_kernel<<<(P_*N_ + 63)/64, 64, 0, stream>>>(pirL, pirS, refix, ws, out);
}

// Round 7
// 72.925 us; speedup vs baseline: 2.5968x; 1.4892x over previous
//
#include <hip/hip_runtime.h>
#include <hip/hip_bf16.h>

// T=6, B=2, Q=50 -> P=100 queries; N=8 targets; 72x72 -> 288x288 bilinear
// (align_corners=False, 4x => fixed weights); out C[B,Q,N] = 800 f32.
// R7: R6 minus in-loop barriers (wave-private LDS is self-ordered), plus
// coalesced act-lane mapping: per iter 4 passes x 4 queries, lane = hi*16+cell
// -> 16-lane contiguous tap loads; geometry hoisted out of the pass loop.

#define T_      6
#define P_      100
#define N_      8
#define HIN     72
#define SIN     (HIN*HIN)        // 5184
#define HOUT    288
#define S_OUT   (HOUT*HOUT)      // 82944
#define NQG     7                // query groups of 16 (100 -> 112 padded)
#define NCH     36               // pixel slabs per (t,qg): 2304 px each
#define PART_F  320              // floats per partial slot
#define WS2_OFF (T_*NQG*NCH*PART_F)          // 483840
#define SUMG_OFF (WS2_OFF + T_*NQG*PART_F)   // 497280
#define GCHUNK  8
#define NQUAD   (S_OUT/4)        // 20736 float4 per mask
#define WLDS    6144             // per-wave LDS: actL 2K, actS 2K, g 2K

typedef __attribute__((ext_vector_type(8))) short short8;
typedef __attribute__((ext_vector_type(4))) float f32x4;
typedef __attribute__((ext_vector_type(2))) float f32x2;

__device__ __forceinline__ unsigned cvt_pk_bf16(float lo, float hi) {
    unsigned r;
    asm("v_cvt_pk_bf16_f32 %0, %1, %2" : "=v"(r) : "v"(lo), "v"(hi));
    return r;
}

__device__ __forceinline__ f32x2 sigm2(f32x2 u) {
    f32x2 e;
    e.x = __expf(-u.x);
    e.y = __expf(-u.y);
    f32x2 d = e + 1.0f;
    f32x2 r;
    r.x = __builtin_amdgcn_rcpf(d.x);
    r.y = __builtin_amdgcn_rcpf(d.y);
    return r;
}

#define WRED(x) { x += __shfl_down(x,32); x += __shfl_down(x,16); x += __shfl_down(x,8); \
                  x += __shfl_down(x,4);  x += __shfl_down(x,2);  x += __shfl_down(x,1); }

// ---------------------------------------------------------------------------
// Kernel 1: act pipeline + MFMA. grid = T_*NQG*NCH, 256 threads (4 waves).
// ---------------------------------------------------------------------------
__global__ __launch_bounds__(256) void mfma_partial(
    const float* __restrict__ predL, const float* __restrict__ predS,
    const float* __restrict__ tgt, float* __restrict__ ws)
{
    __shared__ __align__(16) char smem[4*WLDS + 512];
    float* iredN = (float*)(smem + 4*WLDS);        // [4][16]
    float* iredD = (float*)(smem + 4*WLDS + 256);  // [4][16]
    float (*cred)[64][8] = (float (*)[64][8])smem; // aliased over act area (end only)

    const int blk = blockIdx.x;                 // (t*NQG+qg)*NCH + ch
    const int t   = blk / (NQG*NCH);
    const int rem = blk % (NQG*NCH);
    const int qg  = rem / NCH;
    const int ch  = rem % NCH;

    const int lane = threadIdx.x & 63;
    const int wv   = threadIdx.x >> 6;
    char* actL = smem + wv*WLDS;
    char* actS = actL + 2048;
    char* gpl  = actL + 4096;

    // act roles: hi = query subgroup (0..3), cell = 4-px cell (0..15)
    const int hi   = lane >> 4;
    const int cell = lane & 15;
    int qgl[4];
#pragma unroll
    for (int r = 0; r < 4; r++) qgl[r] = min(qg*16 + r*4 + hi, P_-1);

    // g-stage roles: n = lane>>3, f = lane&7 (two float4 each: f and f+8)
    const int gn = lane >> 3, gf = lane & 7;
    const float4* __restrict__ gsrc = (const float4*)tgt + (size_t)(t*8 + gn)*NQUAD;
    const int gwoff = (gn*128 + 8*gf) ^ ((gn&7)<<4);

    // prefill B cols 8..15 (ones column + zeros), static across iters
    if (lane < 16) {
        *(uint2*)(gpl + ((8*128 + 8*lane) ^ 0)) = make_uint2(0x3F803F80u, 0x3F803F80u);
#pragma unroll
        for (int col = 9; col < 16; col++)
            *(uint2*)(gpl + ((col*128 + 8*lane) ^ ((col&7)<<4))) = make_uint2(0u, 0u);
    }

    f32x4 accL = {0.f,0.f,0.f,0.f}, accS = {0.f,0.f,0.f,0.f};
    float iN[4] = {0.f,0.f,0.f,0.f}, iD[4] = {0.f,0.f,0.f,0.f};
    const int arow = lane & 15, kg = lane >> 4;   // MFMA fragment roles

    for (int it = 0; it < 9; it++) {
        const int px0 = ch*2304 + it*256 + wv*64;   // wave's 64-px chunk

        // --- stage g chunk (8 masks x 64 px, bf16, swizzled [n][k]) ---
        {
            const int f4b = px0 >> 2;
            float4 ga = gsrc[f4b + gf];
            float4 gb = gsrc[f4b + gf + 8];
            uint2 pa, pb;
            pa.x = cvt_pk_bf16(ga.x, ga.y); pa.y = cvt_pk_bf16(ga.z, ga.w);
            pb.x = cvt_pk_bf16(gb.x, gb.y); pb.y = cvt_pk_bf16(gb.z, gb.w);
            *(uint2*)(gpl + gwoff) = pa;
            *(uint2*)(gpl + (gwoff ^ 64)) = pb;     // base bit6==0 pre-swz
        }

        // --- geometry: shared by all 4 passes (depends only on cell) ---
        const unsigned p = px0 + 4*cell;
        const int row  = p / 288u;
        const int col4 = (p % 288u) >> 2;
        const int ry = row & 3, j = row >> 2;
        int y0 = (ry < 2) ? j-1 : j;
        int y1 = y0 + 1;
        y0 = max(y0, 0); y1 = min(y1, HIN-1);
        const float wt = 0.375f + 0.5f*(float)(ry>>1) - 0.25f*(float)(ry&1);
        const float wb = 1.0f - wt;
        const int im1 = max(col4-1, 0), ip1 = min(col4+1, HIN-1);
        const int o0 = y0*HIN, o1 = y1*HIN;

        // --- 4 passes x 4 queries: coalesced 16-lane tap loads ---
#pragma unroll
        for (int r = 0; r < 4; r++) {
            const float* __restrict__ pLq = predL + ((size_t)t*P_ + qgl[r])*SIN;
            const float* __restrict__ pSq = predS + ((size_t)t*P_ + qgl[r])*SIN;

            f32x2 tm, tc, tp, bm, bc, bp;   // (L,S) pairs
            tm.x = pLq[o0+im1];  tm.y = pSq[o0+im1];
            tc.x = pLq[o0+col4]; tc.y = pSq[o0+col4];
            tp.x = pLq[o0+ip1];  tp.y = pSq[o0+ip1];
            bm.x = pLq[o1+im1];  bm.y = pSq[o1+im1];
            bc.x = pLq[o1+col4]; bc.y = pSq[o1+col4];
            bp.x = pLq[o1+ip1];  bp.y = pSq[o1+ip1];

            f32x2 vm = tm*wt + bm*wb;
            f32x2 vc = tc*wt + bc*wb;
            f32x2 vp = tp*wt + bp*wb;
            f32x2 u0 = vm*0.375f + vc*0.625f;
            f32x2 u1 = vm*0.125f + vc*0.875f;
            f32x2 u2 = vc*0.875f + vp*0.125f;
            f32x2 u3 = vc*0.625f + vp*0.375f;

            f32x2 a0 = sigm2(u0), a1 = sigm2(u1), a2 = sigm2(u2), a3 = sigm2(u3);

            // conditioned IoU (x = L, y = S), per-pass accumulators
            {
                float pl, ps;
                pl = (u0.x > 0.f) ? a0.x : 0.f; ps = (u0.y > 0.f) ? a0.y : 0.f;
                iN[r] = fmaf(pl, ps, iN[r]); iD[r] += pl;
                pl = (u1.x > 0.f) ? a1.x : 0.f; ps = (u1.y > 0.f) ? a1.y : 0.f;
                iN[r] = fmaf(pl, ps, iN[r]); iD[r] += pl;
                pl = (u2.x > 0.f) ? a2.x : 0.f; ps = (u2.y > 0.f) ? a2.y : 0.f;
                iN[r] = fmaf(pl, ps, iN[r]); iD[r] += pl;
                pl = (u3.x > 0.f) ? a3.x : 0.f; ps = (u3.y > 0.f) ? a3.y : 0.f;
                iN[r] = fmaf(pl, ps, iN[r]); iD[r] += pl;
            }

            uint2 wl, wsv;
            wl.x  = cvt_pk_bf16(a0.x, a1.x); wl.y  = cvt_pk_bf16(a2.x, a3.x);
            wsv.x = cvt_pk_bf16(a0.y, a1.y); wsv.y = cvt_pk_bf16(a2.y, a3.y);
            const int qloc = r*4 + hi;
            const int aoff = (qloc*128 + 8*cell) ^ ((qloc&7)<<4);
            *(uint2*)(actL + aoff) = wl;
            *(uint2*)(actS + aoff) = wsv;
        }

        // --- MFMA: 2 k-steps x 2 tensors (wave-private LDS: no barrier) ---
#pragma unroll
        for (int ks = 0; ks < 2; ks++) {
            const int fo = (arow*128 + 64*ks + 16*kg) ^ ((arow&7)<<4);
            short8 fAL = *(const short8*)(actL + fo);
            short8 fAS = *(const short8*)(actS + fo);
            short8 fB  = *(const short8*)(gpl  + fo);
            accL = __builtin_amdgcn_mfma_f32_16x16x32_bf16(fAL, fB, accL, 0, 0, 0);
            accS = __builtin_amdgcn_mfma_f32_16x16x32_bf16(fAS, fB, accS, 0, 0, 0);
        }
    }

    // --- iou reduce within 16-lane cell groups (lane cell==0 holds sum) ---
#pragma unroll
    for (int r = 0; r < 4; r++) {
        iN[r] += __shfl_down(iN[r], 1); iN[r] += __shfl_down(iN[r], 2);
        iN[r] += __shfl_down(iN[r], 4); iN[r] += __shfl_down(iN[r], 8);
        iD[r] += __shfl_down(iD[r], 1); iD[r] += __shfl_down(iD[r], 2);
        iD[r] += __shfl_down(iD[r], 4); iD[r] += __shfl_down(iD[r], 8);
    }

    __syncthreads();       // done with act LDS; cred aliases it now
#pragma unroll
    for (int e = 0; e < 4; e++) { cred[wv][lane][e] = accL[e]; cred[wv][lane][4+e] = accS[e]; }
    if (cell == 0) {
#pragma unroll
        for (int r = 0; r < 4; r++) {
            iredN[wv*16 + r*4 + hi] = iN[r];
            iredD[wv*16 + r*4 + hi] = iD[r];
        }
    }
    __syncthreads();

    float* wsb = ws + (size_t)blk * PART_F;
    if (threadIdx.x < 64) {
        const int l = threadIdx.x;
        const int colx = l & 15, rb = (l >> 4) * 4;
        if (colx < 9) {
#pragma unroll
            for (int e = 0; e < 4; e++) {
                const float sLv = cred[0][l][e]+cred[1][l][e]+cred[2][l][e]+cred[3][l][e];
                const float sSv = cred[0][l][4+e]+cred[1][l][4+e]+cred[2][l][4+e]+cred[3][l][4+e];
                wsb[colx*16 + rb + e] = sLv;
                wsb[144 + colx*16 + rb + e] = sSv;
            }
        }
    }
    if (threadIdx.x < 16) {
        wsb[288 + threadIdx.x] = iredN[threadIdx.x] + iredN[16+threadIdx.x]
                               + iredN[32+threadIdx.x] + iredN[48+threadIdx.x];
        wsb[304 + threadIdx.x] = iredD[threadIdx.x] + iredD[16+threadIdx.x]
                               + iredD[32+threadIdx.x] + iredD[48+threadIdx.x];
    }
}

// ---------------------------------------------------------------------------
// Kernel 2: per-(t,n) target mask partial sums (f32 exact)
// ---------------------------------------------------------------------------
__global__ __launch_bounds__(256) void sumg_kernel(
    const float* __restrict__ tgt, float* __restrict__ ws)
{
    const int blk  = blockIdx.x;             // (t*8+n)*GCHUNK + c
    const int mask = blk / GCHUNK;
    const int c    = blk % GCHUNK;
    const float4* __restrict__ g = (const float4*)(tgt + (size_t)mask*S_OUT);
    const int per = NQUAD / GCHUNK;          // 2592
    float s = 0.f;
    const int end = (c+1)*per;
    for (int idx = c*per + threadIdx.x; idx < end; idx += 256) {
        float4 v = g[idx];
        s += v.x + v.y + v.z + v.w;
    }
    WRED(s);
    __shared__ float r[4];
    if ((threadIdx.x & 63) == 0) r[threadIdx.x >> 6] = s;
    __syncthreads();
    if (threadIdx.x == 0) ws[SUMG_OFF + blk] = r[0]+r[1]+r[2]+r[3];
}

// ---------------------------------------------------------------------------
// Kernel 3: reduce NCH chunk partials -> per-(t,qg) sums
// ---------------------------------------------------------------------------
__global__ __launch_bounds__(320) void reduce_kernel(float* __restrict__ ws)
{
    const int tq = blockIdx.x;               // t*NQG + qg
    for (int s = threadIdx.x; s < PART_F; s += 320) {
        float acc = 0.f;
        const float* base = ws + (size_t)tq*NCH*PART_F + s;
#pragma unroll 4
        for (int c = 0; c < NCH; c++) acc += base[(size_t)c*PART_F];
        ws[WS2_OFF + (size_t)tq*PART_F + s] = acc;
    }
}

// ---------------------------------------------------------------------------
// Kernel 4: finalize 800 outputs
// ---------------------------------------------------------------------------
__global__ __launch_bounds__(64) void final_kernel(
    const float* __restrict__ pirL, const float* __restrict__ pirS,
    const int* __restrict__ refidx, const float* __restrict__ ws,
    float* __restrict__ out)
{
    const int gid = blockIdx.x*64 + threadIdx.x;
    if (gid >= P_*N_) return;
    const int p = gid >> 3, n = gid & 7;
    const int b = p / 50, qloc = p % 50;
    const int qg = p >> 4, row = p & 15;
    const int rg0 = refidx[0], rg1 = refidx[1] + 4;   // ref_indices[b] + b*(N/B)
    const bool isref = (n == rg0) || (n == rg1);

    float acc = 0.f;
    for (int t = 0; t < T_; t++) {
        const float* b2 = ws + WS2_OFF + (size_t)(t*NQG + qg)*PART_F;
        const float dL = b2[n*16 + row];
        const float sL = b2[128 + row];          // ones column (col 8)
        const float dS = b2[144 + n*16 + row];
        const float sS = b2[144 + 128 + row];
        const float iN = b2[288 + row];
        const float iD = b2[304 + row];
        float gS = 0.f;
#pragma unroll
        for (int c = 0; c < GCHUNK; c++) gS += ws[SUMG_OFF + (t*8+n)*GCHUNK + c];

        const float diceL = (2.f*dL + 1.f) / (sL + gS + 1.f);
        const float diceS = (2.f*dS + 1.f) / (sS + gS + 1.f);
        const float iou   = (iN + 1.f) / (iD + 1.f);
        const int ib = ((t*2 + b)*50 + qloc)*2;
        const float l0 = pirL[ib], l1 = pirL[ib+1];
        const float m0 = pirS[ib], m1 = pirS[ib+1];
        const float pl = isref ? 1.f/(1.f + __expf(l1 - l0)) : 1.f/(1.f + __expf(l0 - l1));
        const float ps = isref ? 1.f/(1.f + __expf(m1 - m0)) : 1.f/(1.f + __expf(m0 - m1));
        acc += diceL + diceS + iou + pl + ps;
    }
    out[gid] = -acc * (1.0f / (float)T_);
}

extern "C" void kernel_launch(void* const* d_in, const int* in_sizes, int n_in,
                              void* d_out, int out_size, void* d_ws, size_t ws_size,
                              hipStream_t stream) {
    const float* predL = (const float*)d_in[0];   // [6,2,50,72,72]
    const float* predS = (const float*)d_in[1];   // [6,2,50,72,72]
    const float* pirL  = (const float*)d_in[2];   // [6,2,50,2]
    const float* pirS  = (const float*)d_in[3];   // [6,2,50,2]
    const float* tgt   = (const float*)d_in[4];   // [6,8,288,288]
    const int*   refix = (const int*)d_in[5];     // [2]
    float* ws  = (float*)d_ws;                    // ~497,664 floats (~1.99 MB)
    float* out = (float*)d_out;                   // 800 floats

    mfma_partial<<<T_*NQG*NCH, 256, 0, stream>>>(predL, predS, tgt, ws);
    sumg_kernel<<<T_*N_*GCHUNK, 256, 0, stream>>>(tgt, ws);
    reduce_kernel<<<T_*NQG, 320, 0, stream>>>(ws);
    final_kernel<<<(P_*N_ + 63)/64, 64, 0, stream>>>(pirL, pirS, refix, ws, out);
}

// Round 8
// 66.915 us; speedup vs baseline: 2.8300x; 1.0898x over previous
//
#include <hip/hip_runtime.h>
#include <hip/hip_bf16.h>

// T=6, B=2, Q=50 -> P=100 queries; N=8 targets; 72x72 -> 288x288 bilinear
// (align_corners=False, 4x => fixed weights); out C[B,Q,N] = 800 f32.
// R8: R7 + (1) all-pass tap-load hoisting w/ __launch_bounds__(256,4) for ILP,
// (2) -log2e folded into row-interp weights => sigmoid = rcp(1+exp2(m)),
// (3) packed f32x2 IoU accumulation.

#define T_      6
#define P_      100
#define N_      8
#define HIN     72
#define SIN     (HIN*HIN)        // 5184
#define HOUT    288
#define S_OUT   (HOUT*HOUT)      // 82944
#define NQG     7                // query groups of 16 (100 -> 112 padded)
#define NCH     36               // pixel slabs per (t,qg): 2304 px each
#define PART_F  320              // floats per partial slot
#define WS2_OFF (T_*NQG*NCH*PART_F)          // 483840
#define SUMG_OFF (WS2_OFF + T_*NQG*PART_F)   // 497280
#define GCHUNK  8
#define NQUAD   (S_OUT/4)        // 20736 float4 per mask
#define WLDS    6144             // per-wave LDS: actL 2K, actS 2K, g 2K
#define NLOG2E  (-1.4426950408889634f)

typedef __attribute__((ext_vector_type(8))) short short8;
typedef __attribute__((ext_vector_type(4))) float f32x4;
typedef __attribute__((ext_vector_type(2))) float f32x2;

__device__ __forceinline__ unsigned cvt_pk_bf16(float lo, float hi) {
    unsigned r;
    asm("v_cvt_pk_bf16_f32 %0, %1, %2" : "=v"(r) : "v"(lo), "v"(hi));
    return r;
}

// a = sigmoid(u) where m = -log2e*u  =>  a = 1/(1+2^m)
__device__ __forceinline__ f32x2 sigm2m(f32x2 m) {
    f32x2 e;
    e.x = __builtin_amdgcn_exp2f(m.x);
    e.y = __builtin_amdgcn_exp2f(m.y);
    f32x2 d = e + 1.0f;
    f32x2 r;
    r.x = __builtin_amdgcn_rcpf(d.x);
    r.y = __builtin_amdgcn_rcpf(d.y);
    return r;
}

#define WRED(x) { x += __shfl_down(x,32); x += __shfl_down(x,16); x += __shfl_down(x,8); \
                  x += __shfl_down(x,4);  x += __shfl_down(x,2);  x += __shfl_down(x,1); }

// ---------------------------------------------------------------------------
// Kernel 1: act pipeline + MFMA. grid = T_*NQG*NCH, 256 threads (4 waves).
// ---------------------------------------------------------------------------
__global__ __launch_bounds__(256, 4) void mfma_partial(
    const float* __restrict__ predL, const float* __restrict__ predS,
    const float* __restrict__ tgt, float* __restrict__ ws)
{
    __shared__ __align__(16) char smem[4*WLDS + 512];
    float* iredN = (float*)(smem + 4*WLDS);        // [4][16]
    float* iredD = (float*)(smem + 4*WLDS + 256);  // [4][16]
    float (*cred)[64][8] = (float (*)[64][8])smem; // aliased over act area (end only)

    const int blk = blockIdx.x;                 // (t*NQG+qg)*NCH + ch
    const int t   = blk / (NQG*NCH);
    const int rem = blk % (NQG*NCH);
    const int qg  = rem / NCH;
    const int ch  = rem % NCH;

    const int lane = threadIdx.x & 63;
    const int wv   = threadIdx.x >> 6;
    char* actL = smem + wv*WLDS;
    char* actS = actL + 2048;
    char* gpl  = actL + 4096;

    // act roles: hi = query subgroup (0..3), cell = 4-px cell (0..15)
    const int hi   = lane >> 4;
    const int cell = lane & 15;
    const float* __restrict__ pLb[4];
    const float* __restrict__ pSb[4];
#pragma unroll
    for (int r = 0; r < 4; r++) {
        const int qv = min(qg*16 + r*4 + hi, P_-1);
        pLb[r] = predL + ((size_t)t*P_ + qv)*SIN;
        pSb[r] = predS + ((size_t)t*P_ + qv)*SIN;
    }

    // g-stage roles: n = lane>>3, f = lane&7 (two float4 each: f and f+8)
    const int gn = lane >> 3, gf = lane & 7;
    const float4* __restrict__ gsrc = (const float4*)tgt + (size_t)(t*8 + gn)*NQUAD;
    const int gwoff = (gn*128 + 8*gf) ^ ((gn&7)<<4);

    // prefill B cols 8..15 (ones column + zeros), static across iters
    if (lane < 16) {
        *(uint2*)(gpl + ((8*128 + 8*lane) ^ 0)) = make_uint2(0x3F803F80u, 0x3F803F80u);
#pragma unroll
        for (int col = 9; col < 16; col++)
            *(uint2*)(gpl + ((col*128 + 8*lane) ^ ((col&7)<<4))) = make_uint2(0u, 0u);
    }

    f32x4 accL = {0.f,0.f,0.f,0.f}, accS = {0.f,0.f,0.f,0.f};
    f32x2 iN2[4], iD2[4];
#pragma unroll
    for (int r = 0; r < 4; r++) { iN2[r] = (f32x2)(0.f); iD2[r] = (f32x2)(0.f); }
    const int arow = lane & 15, kg = lane >> 4;   // MFMA fragment roles

    for (int it = 0; it < 9; it++) {
        const int px0 = ch*2304 + it*256 + wv*64;   // wave's 64-px chunk

        // --- stage g chunk (8 masks x 64 px, bf16, swizzled [n][k]) ---
        {
            const int f4b = px0 >> 2;
            float4 ga = gsrc[f4b + gf];
            float4 gb = gsrc[f4b + gf + 8];
            uint2 pa, pb;
            pa.x = cvt_pk_bf16(ga.x, ga.y); pa.y = cvt_pk_bf16(ga.z, ga.w);
            pb.x = cvt_pk_bf16(gb.x, gb.y); pb.y = cvt_pk_bf16(gb.z, gb.w);
            *(uint2*)(gpl + gwoff) = pa;
            *(uint2*)(gpl + (gwoff ^ 64)) = pb;     // base bit6==0 pre-swz
        }

        // --- geometry: shared by all 4 passes (depends only on cell) ---
        const unsigned p = px0 + 4*cell;
        const int row  = p / 288u;
        const int col4 = (p % 288u) >> 2;
        const int ry = row & 3, j = row >> 2;
        int y0 = (ry < 2) ? j-1 : j;
        int y1 = y0 + 1;
        y0 = max(y0, 0); y1 = min(y1, HIN-1);
        const float wt = 0.375f + 0.5f*(float)(ry>>1) - 0.25f*(float)(ry&1);
        const float wtm = wt * NLOG2E;              // fold -log2e into row weights
        const float wbm = (1.0f - wt) * NLOG2E;
        const int im1 = max(col4-1, 0), ip1 = min(col4+1, HIN-1);
        const int o0 = y0*HIN, o1 = y1*HIN;

        // --- hoist ALL taps for the 4 passes (48 loads in flight) ---
        f32x2 tap[4][6];   // [pass][tm,tc,tp,bm,bc,bp] ; .x = L, .y = S
#pragma unroll
        for (int r = 0; r < 4; r++) {
            const float* __restrict__ pLq = pLb[r];
            const float* __restrict__ pSq = pSb[r];
            tap[r][0].x = pLq[o0+im1];  tap[r][0].y = pSq[o0+im1];
            tap[r][1].x = pLq[o0+col4]; tap[r][1].y = pSq[o0+col4];
            tap[r][2].x = pLq[o0+ip1];  tap[r][2].y = pSq[o0+ip1];
            tap[r][3].x = pLq[o1+im1];  tap[r][3].y = pSq[o1+im1];
            tap[r][4].x = pLq[o1+col4]; tap[r][4].y = pSq[o1+col4];
            tap[r][5].x = pLq[o1+ip1];  tap[r][5].y = pSq[o1+ip1];
        }

        // --- 4 passes x 4 queries, compute from registers ---
#pragma unroll
        for (int r = 0; r < 4; r++) {
            f32x2 vm = tap[r][0]*wtm + tap[r][3]*wbm;   // m-scale folded
            f32x2 vc = tap[r][1]*wtm + tap[r][4]*wbm;
            f32x2 vp = tap[r][2]*wtm + tap[r][5]*wbm;
            f32x2 m0 = vm*0.375f + vc*0.625f;
            f32x2 m1 = vm*0.125f + vc*0.875f;
            f32x2 m2 = vc*0.875f + vp*0.125f;
            f32x2 m3 = vc*0.625f + vp*0.375f;

            f32x2 a0 = sigm2m(m0), a1 = sigm2m(m1), a2 = sigm2m(m2), a3 = sigm2m(m3);

            // conditioned IoU: u>0 <=> m<0 ; packed accumulate
            f32x2 pl01, ps01, pl23, ps23;
            pl01.x = (m0.x < 0.f) ? a0.x : 0.f;  pl01.y = (m1.x < 0.f) ? a1.x : 0.f;
            ps01.x = (m0.y < 0.f) ? a0.y : 0.f;  ps01.y = (m1.y < 0.f) ? a1.y : 0.f;
            pl23.x = (m2.x < 0.f) ? a2.x : 0.f;  pl23.y = (m3.x < 0.f) ? a3.x : 0.f;
            ps23.x = (m2.y < 0.f) ? a2.y : 0.f;  ps23.y = (m3.y < 0.f) ? a3.y : 0.f;
            iN2[r] = pl01*ps01 + iN2[r];
            iN2[r] = pl23*ps23 + iN2[r];
            iD2[r] = iD2[r] + pl01 + pl23;

            uint2 wl, wsv;
            wl.x  = cvt_pk_bf16(a0.x, a1.x); wl.y  = cvt_pk_bf16(a2.x, a3.x);
            wsv.x = cvt_pk_bf16(a0.y, a1.y); wsv.y = cvt_pk_bf16(a2.y, a3.y);
            const int qloc = r*4 + hi;
            const int aoff = (qloc*128 + 8*cell) ^ ((qloc&7)<<4);
            *(uint2*)(actL + aoff) = wl;
            *(uint2*)(actS + aoff) = wsv;
        }

        // --- MFMA: 2 k-steps x 2 tensors (wave-private LDS: no barrier) ---
#pragma unroll
        for (int ks = 0; ks < 2; ks++) {
            const int fo = (arow*128 + 64*ks + 16*kg) ^ ((arow&7)<<4);
            short8 fAL = *(const short8*)(actL + fo);
            short8 fAS = *(const short8*)(actS + fo);
            short8 fB  = *(const short8*)(gpl  + fo);
            accL = __builtin_amdgcn_mfma_f32_16x16x32_bf16(fAL, fB, accL, 0, 0, 0);
            accS = __builtin_amdgcn_mfma_f32_16x16x32_bf16(fAS, fB, accS, 0, 0, 0);
        }
    }

    // --- iou reduce within 16-lane cell groups (lane cell==0 holds sum) ---
    float iN[4], iD[4];
#pragma unroll
    for (int r = 0; r < 4; r++) {
        iN[r] = iN2[r].x + iN2[r].y;
        iD[r] = iD2[r].x + iD2[r].y;
        iN[r] += __shfl_down(iN[r], 1); iN[r] += __shfl_down(iN[r], 2);
        iN[r] += __shfl_down(iN[r], 4); iN[r] += __shfl_down(iN[r], 8);
        iD[r] += __shfl_down(iD[r], 1); iD[r] += __shfl_down(iD[r], 2);
        iD[r] += __shfl_down(iD[r], 4); iD[r] += __shfl_down(iD[r], 8);
    }

    __syncthreads();       // done with act LDS; cred aliases it now
#pragma unroll
    for (int e = 0; e < 4; e++) { cred[wv][lane][e] = accL[e]; cred[wv][lane][4+e] = accS[e]; }
    if (cell == 0) {
#pragma unroll
        for (int r = 0; r < 4; r++) {
            iredN[wv*16 + r*4 + hi] = iN[r];
            iredD[wv*16 + r*4 + hi] = iD[r];
        }
    }
    __syncthreads();

    float* wsb = ws + (size_t)blk * PART_F;
    if (threadIdx.x < 64) {
        const int l = threadIdx.x;
        const int colx = l & 15, rb = (l >> 4) * 4;
        if (colx < 9) {
#pragma unroll
            for (int e = 0; e < 4; e++) {
                const float sLv = cred[0][l][e]+cred[1][l][e]+cred[2][l][e]+cred[3][l][e];
                const float sSv = cred[0][l][4+e]+cred[1][l][4+e]+cred[2][l][4+e]+cred[3][l][4+e];
                wsb[colx*16 + rb + e] = sLv;
                wsb[144 + colx*16 + rb + e] = sSv;
            }
        }
    }
    if (threadIdx.x < 16) {
        wsb[288 + threadIdx.x] = iredN[threadIdx.x] + iredN[16+threadIdx.x]
                               + iredN[32+threadIdx.x] + iredN[48+threadIdx.x];
        wsb[304 + threadIdx.x] = iredD[threadIdx.x] + iredD[16+threadIdx.x]
                               + iredD[32+threadIdx.x] + iredD[48+threadIdx.x];
    }
}

// ---------------------------------------------------------------------------
// Kernel 2: per-(t,n) target mask partial sums (f32 exact)
// ---------------------------------------------------------------------------
__global__ __launch_bounds__(256) void sumg_kernel(
    const float* __restrict__ tgt, float* __restrict__ ws)
{
    const int blk  = blockIdx.x;             // (t*8+n)*GCHUNK + c
    const int mask = blk / GCHUNK;
    const int c    = blk % GCHUNK;
    const float4* __restrict__ g = (const float4*)(tgt + (size_t)mask*S_OUT);
    const int per = NQUAD / GCHUNK;          // 2592
    float s = 0.f;
    const int end = (c+1)*per;
    for (int idx = c*per + threadIdx.x; idx < end; idx += 256) {
        float4 v = g[idx];
        s += v.x + v.y + v.z + v.w;
    }
    WRED(s);
    __shared__ float r[4];
    if ((threadIdx.x & 63) == 0) r[threadIdx.x >> 6] = s;
    __syncthreads();
    if (threadIdx.x == 0) ws[SUMG_OFF + blk] = r[0]+r[1]+r[2]+r[3];
}

// ---------------------------------------------------------------------------
// Kernel 3: reduce NCH chunk partials -> per-(t,qg) sums
// ---------------------------------------------------------------------------
__global__ __launch_bounds__(320) void reduce_kernel(float* __restrict__ ws)
{
    const int tq = blockIdx.x;               // t*NQG + qg
    for (int s = threadIdx.x; s < PART_F; s += 320) {
        float acc = 0.f;
        const float* base = ws + (size_t)tq*NCH*PART_F + s;
#pragma unroll 4
        for (int c = 0; c < NCH; c++) acc += base[(size_t)c*PART_F];
        ws[WS2_OFF + (size_t)tq*PART_F + s] = acc;
    }
}

// ---------------------------------------------------------------------------
// Kernel 4: finalize 800 outputs
// ---------------------------------------------------------------------------
__global__ __launch_bounds__(64) void final_kernel(
    const float* __restrict__ pirL, const float* __restrict__ pirS,
    const int* __restrict__ refidx, const float* __restrict__ ws,
    float* __restrict__ out)
{
    const int gid = blockIdx.x*64 + threadIdx.x;
    if (gid >= P_*N_) return;
    const int p = gid >> 3, n = gid & 7;
    const int b = p / 50, qloc = p % 50;
    const int qg = p >> 4, row = p & 15;
    const int rg0 = refidx[0], rg1 = refidx[1] + 4;   // ref_indices[b] + b*(N/B)
    const bool isref = (n == rg0) || (n == rg1);

    float acc = 0.f;
    for (int t = 0; t < T_; t++) {
        const float* b2 = ws + WS2_OFF + (size_t)(t*NQG + qg)*PART_F;
        const float dL = b2[n*16 + row];
        const float sL = b2[128 + row];          // ones column (col 8)
        const float dS = b2[144 + n*16 + row];
        const float sS = b2[144 + 128 + row];
        const float iN = b2[288 + row];
        const float iD = b2[304 + row];
        float gS = 0.f;
#pragma unroll
        for (int c = 0; c < GCHUNK; c++) gS += ws[SUMG_OFF + (t*8+n)*GCHUNK + c];

        const float diceL = (2.f*dL + 1.f) / (sL + gS + 1.f);
        const float diceS = (2.f*dS + 1.f) / (sS + gS + 1.f);
        const float iou   = (iN + 1.f) / (iD + 1.f);
        const int ib = ((t*2 + b)*50 + qloc)*2;
        const float l0 = pirL[ib], l1 = pirL[ib+1];
        const float m0 = pirS[ib], m1 = pirS[ib+1];
        const float pl = isref ? 1.f/(1.f + __expf(l1 - l0)) : 1.f/(1.f + __expf(l0 - l1));
        const float ps = isref ? 1.f/(1.f + __expf(m1 - m0)) : 1.f/(1.f + __expf(m0 - m1));
        acc += diceL + diceS + iou + pl + ps;
    }
    out[gid] = -acc * (1.0f / (float)T_);
}

extern "C" void kernel_launch(void* const* d_in, const int* in_sizes, int n_in,
                              void* d_out, int out_size, void* d_ws, size_t ws_size,
                              hipStream_t stream) {
    const float* predL = (const float*)d_in[0];   // [6,2,50,72,72]
    const float* predS = (const float*)d_in[1];   // [6,2,50,72,72]
    const float* pirL  = (const float*)d_in[2];   // [6,2,50,2]
    const float* pirS  = (const float*)d_in[3];   // [6,2,50,2]
    const float* tgt   = (const float*)d_in[4];   // [6,8,288,288]
    const int*   refix = (const int*)d_in[5];     // [2]
    float* ws  = (float*)d_ws;                    // ~497,664 floats (~1.99 MB)
    float* out = (float*)d_out;                   // 800 floats

    mfma_partial<<<T_*NQG*NCH, 256, 0, stream>>>(predL, predS, tgt, ws);
    sumg_kernel<<<T_*N_*GCHUNK, 256, 0, stream>>>(tgt, ws);
    reduce_kernel<<<T_*NQG, 320, 0, stream>>>(ws);
    final_kernel<<<(P_*N_ + 63)/64, 64, 0, stream>>>(pirL, pirS, refix, ws, out);
}